// Round 6
// baseline (375.111 us; speedup 1.0000x reference)
//
#include <hip/hip_runtime.h>

#define NPIL 12000
#define NPTS 100
#define CIN 9
#define COUT 32

__launch_bounds__(256, 4)
__global__ void pfn_kernel(const float* __restrict__ px, const float* __restrict__ py,
                           const float* __restrict__ pz, const float* __restrict__ pi,
                           const int*   __restrict__ nvox,
                           const float* __restrict__ xs, const float* __restrict__ ys,
                           const float* __restrict__ mk,
                           const float* __restrict__ W,  const float* __restrict__ gma,
                           const float* __restrict__ bta, const float* __restrict__ bmean,
                           const float* __restrict__ bvar,
                           float* __restrict__ out) {
    __shared__ float lin8[NPTS][8];   // [n][x,y,z,i,xs,ys,m,pad] — 3.2 KB
    __shared__ float lmean[3];
    __shared__ int   lmax[COUT];

    const int p = blockIdx.x;
    const int t = threadIdx.x;
    const float fnv = (float)nvox[p];     // hoisted off the inter-barrier critical path

    // ---- stage: threads 0..99 load their point's 7 scalars (coalesced) ----
    if (t < NPTS) {
        const size_t o = (size_t)p * NPTS + t;
        lin8[t][0] = px[o]; lin8[t][1] = py[o]; lin8[t][2] = pz[o]; lin8[t][3] = pi[o];
        lin8[t][4] = xs[o]; lin8[t][5] = ys[o]; lin8[t][6] = mk[o];
    }
    if (t >= 224) lmax[t - 224] = 0;      // ReLU output >= 0 -> 0 is max-identity
    __syncthreads();

    // ---- unmasked x/y/z sums over all 100 slots, / num_voxels ----
    if (t < 96) {
        int c = t >> 5, j = t & 31;
        float v = lin8[j][c] + lin8[j + 32][c] + lin8[j + 64][c];
        if (j < 4) v += lin8[j + 96][c];
        v += __shfl_xor(v, 16);
        v += __shfl_xor(v, 8);
        v += __shfl_xor(v, 4);
        v += __shfl_xor(v, 2);
        v += __shfl_xor(v, 1);
        if (j == 0) lmean[c] = v / fnv;
    }

    // ---- per-thread channel quad q: channels 4q..4q+3; fold BN into weights ----
    const int q = t & 7;
    float wq[4][CIN], bq[4];
    #pragma unroll
    for (int j = 0; j < 4; ++j) {
        int u = 4 * q + j;
        float s = rsqrtf(bvar[u] + 1e-3f) * gma[u];
        bq[j] = bta[u] - bmean[u] * s;
        #pragma unroll
        for (int k = 0; k < CIN; ++k) wq[j][k] = W[u * CIN + k] * s;
    }
    __syncthreads();

    const float mx = lmean[0], my = lmean[1], mz = lmean[2];
    float* outp = out + (size_t)p * (NPTS * 64);
    float4 vmax = make_float4(0.f, 0.f, 0.f, 0.f);

    // each 8-thread group owns point n; thread covers n = t>>3, +32, +64, +96
    for (int n = (t >> 3); n < NPTS; n += 32) {
        float4 a  = *(const float4*)&lin8[n][0];   // x,y,z,i
        float4 c4 = *(const float4*)&lin8[n][4];   // xs,ys,m,pad
        const float f0 = a.x, f1 = a.y, f2 = a.z, f3 = a.w;
        const float f4 = a.x - mx, f5 = a.y - my, f6 = a.z - mz;
        const float f7 = a.x - c4.x, f8 = a.y - c4.y;
        const float m = c4.z;
        float4 v;
        #pragma unroll
        for (int j = 0; j < 4; ++j) {
            float dot = f0 * wq[j][0] + f1 * wq[j][1] + f2 * wq[j][2]
                      + f3 * wq[j][3] + f4 * wq[j][4] + f5 * wq[j][5]
                      + f6 * wq[j][6] + f7 * wq[j][7] + f8 * wq[j][8];
            (&v.x)[j] = fmaxf(fmaf(m, dot, bq[j]), 0.f);
        }
        *(float4*)(outp + n * 64 + 4 * q) = v;     // pure float4 store, 16B/lane
        vmax.x = fmaxf(vmax.x, v.x); vmax.y = fmaxf(vmax.y, v.y);
        vmax.z = fmaxf(vmax.z, v.z); vmax.w = fmaxf(vmax.w, v.w);
    }

    // ---- reduce vmax across the 8 lanes sharing q (lane bits 3,4,5) ----
    #pragma unroll
    for (int msk = 8; msk <= 32; msk <<= 1) {
        vmax.x = fmaxf(vmax.x, __shfl_xor(vmax.x, msk));
        vmax.y = fmaxf(vmax.y, __shfl_xor(vmax.y, msk));
        vmax.z = fmaxf(vmax.z, __shfl_xor(vmax.z, msk));
        vmax.w = fmaxf(vmax.w, __shfl_xor(vmax.w, msk));
    }
    if ((t & 63) < 8) {                            // one lane per (wave, q)
        atomicMax(&lmax[4 * q + 0], __float_as_int(vmax.x));
        atomicMax(&lmax[4 * q + 1], __float_as_int(vmax.y));
        atomicMax(&lmax[4 * q + 2], __float_as_int(vmax.z));
        atomicMax(&lmax[4 * q + 3], __float_as_int(vmax.w));
    }
    __syncthreads();

    // ---- upper halves: out[p][n][32..63] = broadcast max (float4 rows) ----
    const float4* lmax4 = (const float4*)lmax;     // bits already hold float max
    for (int idx = t; idx < NPTS * 8; idx += 256) {
        int n = idx >> 3, r = idx & 7;
        ((float4*)(outp + n * 64 + 32))[r] = lmax4[r];
    }
}

extern "C" void kernel_launch(void* const* d_in, const int* in_sizes, int n_in,
                              void* d_out, int out_size, void* d_ws, size_t ws_size,
                              hipStream_t stream) {
    const float* px  = (const float*)d_in[0];
    const float* py  = (const float*)d_in[1];
    const float* pz  = (const float*)d_in[2];
    const float* pi  = (const float*)d_in[3];
    const int*   nv  = (const int*)  d_in[4];
    const float* xs  = (const float*)d_in[5];
    const float* ys  = (const float*)d_in[6];
    const float* mk  = (const float*)d_in[7];
    const float* W   = (const float*)d_in[8];
    const float* gma = (const float*)d_in[9];
    const float* bta = (const float*)d_in[10];
    const float* bmn = (const float*)d_in[11];
    const float* bvr = (const float*)d_in[12];
    float* out = (float*)d_out;

    pfn_kernel<<<dim3(NPIL), dim3(256), 0, stream>>>(
        px, py, pz, pi, nv, xs, ys, mk, W, gma, bta, bmn, bvr, out);
}